// Round 24
// baseline (79.588 us; speedup 1.0000x reference)
//
#include <hip/hip_runtime.h>
#include <hip/hip_bf16.h>

#define BTT 48      // B*T
#define SEQ 512     // spatial tokens
#define DIM 256     // model dim
#define NH  8       // heads
#define HD  32      // head dim
#define QKVD 768    // fused QKV row stride

typedef unsigned short u16;
typedef __attribute__((ext_vector_type(8))) short bf16x8;
typedef __attribute__((ext_vector_type(4))) float f32x4;
typedef __attribute__((ext_vector_type(2))) unsigned int u32x2;

__device__ __forceinline__ float fexp2(float x) {
#if __has_builtin(__builtin_amdgcn_exp2f)
  return __builtin_amdgcn_exp2f(x);
#else
  float r; asm("v_exp_f32 %0, %1" : "=v"(r) : "v"(x)); return r;
#endif
}
__device__ __forceinline__ unsigned cvtpk_bf16(float lo, float hi) {
  unsigned r;
  asm("v_cvt_pk_bf16_f32 %0, %1, %2" : "=v"(r) : "v"(lo), "v"(hi));
  return r;
}

__device__ __forceinline__ u16 f2b(float f) {
  __hip_bfloat16 h = __float2bfloat16(f);
  union { __hip_bfloat16 h; u16 u; } c; c.h = h; return c.u;
}
__device__ __forceinline__ bf16x8 ldfrag8(const u16* p) {   // LDS, 8B-aligned
  union { uint2 u[2]; bf16x8 v; } f;
  f.u[0] = *reinterpret_cast<const uint2*>(p);
  f.u[1] = *reinterpret_cast<const uint2*>(p + 4);
  return f.v;
}
__device__ __forceinline__ bf16x8 ldfrag16(const u16* p) {  // 16B-aligned
  union { uint4 u; bf16x8 v; } f;
  f.u = *reinterpret_cast<const uint4*>(p);
  return f.v;
}

// ---- merged prep: z<4 = weight cvt+transpose+scale; z==4 = sim pack ----
__global__ __launch_bounds__(256) void prep_kernel(const float* __restrict__ W0,
                                                   const float* __restrict__ W1,
                                                   const float* __restrict__ W2,
                                                   const float* __restrict__ W3,
                                                   const float* __restrict__ sim,
                                                   u16* __restrict__ dst,
                                                   float* __restrict__ simT2,
                                                   float sc0) {
  __shared__ float Ls[64][65];
  const int z = blockIdx.z;
  const int t = threadIdx.x;
  if (z == 4) {   // sim[q][k] fp32 -> simT2[k>>2][q][k&3], scaled by log2(e)
    const float LOG2E = 1.4426950408889634f;
    const int b = blockIdx.x * 4 + blockIdx.y;     // 0..15
#pragma unroll
    for (int i = 0; i < 16; ++i) {
      int gid = b * 4096 + i * 256 + t;            // 0..65535
      int q = gid & 511, k4 = gid >> 9;
      float4 v = *reinterpret_cast<const float4*>(&sim[(size_t)q * 512 + k4 * 4]);
      v.x *= LOG2E; v.y *= LOG2E; v.z *= LOG2E; v.w *= LOG2E;
      *reinterpret_cast<float4*>(&simT2[((size_t)k4 * 512 + q) * 4]) = v;
    }
    return;
  }
  const float* W = (z == 0) ? W0 : (z == 1) ? W1 : (z == 2) ? W2 : W3;
  u16* Bt = dst + (size_t)z * DIM * DIM;
  const float sc = (z == 0) ? sc0 : 1.0f;
  const int kt = blockIdx.x * 64, nt = blockIdx.y * 64;
#pragma unroll
  for (int it = 0; it < 4; ++it) {
    int r = (t >> 4) + it * 16;
    int c = (t & 15) * 4;
    float4 v = *reinterpret_cast<const float4*>(&W[(size_t)(kt + r) * 256 + nt + c]);
    Ls[r][c] = v.x; Ls[r][c + 1] = v.y; Ls[r][c + 2] = v.z; Ls[r][c + 3] = v.w;
  }
  __syncthreads();
  const int n = t >> 2, kc = (t & 3) * 16;
  union { uint4 u[2]; u16 s[16]; } ob;
#pragma unroll
  for (int j = 0; j < 16; ++j) ob.s[j] = f2b(Ls[kc + j][n] * sc);
  u16* dp = Bt + (size_t)(nt + n) * 256 + kt + kc;
  *reinterpret_cast<uint4*>(dp)     = ob.u[0];
  *reinterpret_cast<uint4*>(dp + 8) = ob.u[1];
}

// ---- QKV GEMM: BK=32, BN=64 (grid 192x12 = 2304 = 9/CU, zero tail),
// fp32-A fused cvt, XCD-chunked bx-major swizzle ----
__global__ __launch_bounds__(256) void gemm_qkv64n(const float* __restrict__ A,
                                                   const u16* __restrict__ Bt,
                                                   u16* __restrict__ C,
                                                   int M, int N, int K) {
  __shared__ u16 As[128][36];
  __shared__ u16 Bs[64][36];
  const int t = threadIdx.x, lane = t & 63, w = t >> 6;
  const int g = lane >> 4, ln = lane & 15;

  const int gx = gridDim.x, gy = gridDim.y;
  const int flat = blockIdx.x + gx * blockIdx.y;
  const int chunk = (gx * gy) >> 3;
  const int work = (flat & 7) * chunk + (flat >> 3);
  const int bm = (work / gy) * 128, bn = (work % gy) * 64;

  const int wr = (w & 1) * 64, wc = (w >> 1) * 32;
  const f32x4 zf = {0.f, 0.f, 0.f, 0.f};
  f32x4 acc[4][2];
#pragma unroll
  for (int i = 0; i < 4; ++i) { acc[i][0] = zf; acc[i][1] = zf; }

  const int r0 = t >> 2, c8 = (t & 3) * 8;
  uint4 bpre;
  float4 apf0[2], apf1[2];
#pragma unroll
  for (int p = 0; p < 2; ++p) {
    const size_t arow = (size_t)(bm + r0 + p * 64) * K + c8;
    apf0[p] = *reinterpret_cast<const float4*>(A + arow);
    apf1[p] = *reinterpret_cast<const float4*>(A + arow + 4);
  }
  bpre = *reinterpret_cast<const uint4*>(&Bt[(size_t)(bn + r0) * K + c8]);

  for (int k0 = 0; k0 < K; k0 += 32) {
#pragma unroll
    for (int p = 0; p < 2; ++p) {
      const int r = r0 + p * 64;
      uint2 a0, a1;
      a0.x = cvtpk_bf16(apf0[p].x, apf0[p].y);
      a0.y = cvtpk_bf16(apf0[p].z, apf0[p].w);
      a1.x = cvtpk_bf16(apf1[p].x, apf1[p].y);
      a1.y = cvtpk_bf16(apf1[p].z, apf1[p].w);
      *reinterpret_cast<uint2*>(&As[r][c8])     = a0;
      *reinterpret_cast<uint2*>(&As[r][c8 + 4]) = a1;
    }
    {
      union { uint4 u4; uint2 u2[2]; } bv; bv.u4 = bpre;
      *reinterpret_cast<uint2*>(&Bs[r0][c8])     = bv.u2[0];
      *reinterpret_cast<uint2*>(&Bs[r0][c8 + 4]) = bv.u2[1];
    }
    if (k0 + 32 < K) {
#pragma unroll
      for (int p = 0; p < 2; ++p) {
        const size_t arow = (size_t)(bm + r0 + p * 64) * K + k0 + 32 + c8;
        apf0[p] = *reinterpret_cast<const float4*>(A + arow);
        apf1[p] = *reinterpret_cast<const float4*>(A + arow + 4);
      }
      bpre = *reinterpret_cast<const uint4*>(&Bt[(size_t)(bn + r0) * K + k0 + 32 + c8]);
    }
    __syncthreads();
    bf16x8 af[4], bfr[2];
#pragma unroll
    for (int i = 0; i < 4; ++i) af[i]  = ldfrag8(&As[wr + i * 16 + ln][g * 8]);
#pragma unroll
    for (int j = 0; j < 2; ++j) bfr[j] = ldfrag8(&Bs[wc + j * 16 + ln][g * 8]);
#pragma unroll
    for (int i = 0; i < 4; ++i)
#pragma unroll
      for (int j = 0; j < 2; ++j)
        acc[i][j] = __builtin_amdgcn_mfma_f32_16x16x32_bf16(af[i], bfr[j], acc[i][j], 0, 0, 0);
    __syncthreads();
  }
#pragma unroll
  for (int i = 0; i < 4; ++i)
#pragma unroll
    for (int j = 0; j < 2; ++j)
#pragma unroll
      for (int r = 0; r < 4; ++r) {
        const int row = bm + wr + i * 16 + g * 4 + r;
        const int col = bn + wc + j * 16 + ln;
        C[(size_t)row * N + col] = f2b(acc[i][j][r]);
      }
}

// ---- O-projection GEMM: bf16 A, BN=64, BK=64 via split k-half buffers ----
__global__ __launch_bounds__(256) void gemm_o64(const u16* __restrict__ A,
                                                const u16* __restrict__ Bt,
                                                float* __restrict__ C,
                                                int M, int N, int K) {
  __shared__ u16 As[2][128][36];   // [k-half][m][k32 pad36]
  __shared__ u16 Bs[2][64][36];    // [k-half][n][k32 pad36]
  const int t = threadIdx.x, lane = t & 63, w = t >> 6;
  const int g = lane >> 4, ln = lane & 15;

  const int gx = gridDim.x, gy = gridDim.y;
  const int flat = blockIdx.x + gx * blockIdx.y;
  const int chunk = (gx * gy) >> 3;
  const int work = (flat & 7) * chunk + (flat >> 3);
  const int bm = (work / gy) * 128, bn = (work % gy) * 64;

  const int wr = (w & 1) * 64, wc = (w >> 1) * 32;
  const f32x4 zf = {0.f, 0.f, 0.f, 0.f};
  f32x4 acc[4][2];
#pragma unroll
  for (int i = 0; i < 4; ++i) { acc[i][0] = zf; acc[i][1] = zf; }

  const int ra = t >> 2, ca = t & 3;
  const int ch = ca >> 1, co = (ca & 1) * 16;
  uint4 apre[2][2], bpre[2];
#pragma unroll
  for (int p = 0; p < 2; ++p) {
    const size_t arow = (size_t)(bm + ra + p * 64) * K + ca * 16;
    apre[p][0] = *reinterpret_cast<const uint4*>(A + arow);
    apre[p][1] = *reinterpret_cast<const uint4*>(A + arow + 8);
  }
  {
    const size_t brow = (size_t)(bn + ra) * K + ca * 16;
    bpre[0] = *reinterpret_cast<const uint4*>(Bt + brow);
    bpre[1] = *reinterpret_cast<const uint4*>(Bt + brow + 8);
  }

  for (int k0 = 0; k0 < K; k0 += 64) {
#pragma unroll
    for (int p = 0; p < 2; ++p) {
      u16* dst = &As[ch][ra + p * 64][co];
      union { uint4 u4; uint2 u2[2]; } v0, v1;
      v0.u4 = apre[p][0]; v1.u4 = apre[p][1];
      *reinterpret_cast<uint2*>(dst)      = v0.u2[0];
      *reinterpret_cast<uint2*>(dst + 4)  = v0.u2[1];
      *reinterpret_cast<uint2*>(dst + 8)  = v1.u2[0];
      *reinterpret_cast<uint2*>(dst + 12) = v1.u2[1];
    }
    {
      u16* dst = &Bs[ch][ra][co];
      union { uint4 u4; uint2 u2[2]; } v0, v1;
      v0.u4 = bpre[0]; v1.u4 = bpre[1];
      *reinterpret_cast<uint2*>(dst)      = v0.u2[0];
      *reinterpret_cast<uint2*>(dst + 4)  = v0.u2[1];
      *reinterpret_cast<uint2*>(dst + 8)  = v1.u2[0];
      *reinterpret_cast<uint2*>(dst + 12) = v1.u2[1];
    }
    if (k0 + 64 < K) {
#pragma unroll
      for (int p = 0; p < 2; ++p) {
        const size_t arow = (size_t)(bm + ra + p * 64) * K + k0 + 64 + ca * 16;
        apre[p][0] = *reinterpret_cast<const uint4*>(A + arow);
        apre[p][1] = *reinterpret_cast<const uint4*>(A + arow + 8);
      }
      const size_t brow = (size_t)(bn + ra) * K + k0 + 64 + ca * 16;
      bpre[0] = *reinterpret_cast<const uint4*>(Bt + brow);
      bpre[1] = *reinterpret_cast<const uint4*>(Bt + brow + 8);
    }
    __syncthreads();
#pragma unroll
    for (int kk = 0; kk < 2; ++kk) {
      bf16x8 af[4], bfr[2];
#pragma unroll
      for (int i = 0; i < 4; ++i) af[i]  = ldfrag8(&As[kk][wr + i * 16 + ln][g * 8]);
#pragma unroll
      for (int j = 0; j < 2; ++j) bfr[j] = ldfrag8(&Bs[kk][wc + j * 16 + ln][g * 8]);
#pragma unroll
      for (int i = 0; i < 4; ++i)
#pragma unroll
        for (int j = 0; j < 2; ++j)
          acc[i][j] = __builtin_amdgcn_mfma_f32_16x16x32_bf16(af[i], bfr[j], acc[i][j], 0, 0, 0);
    }
    __syncthreads();
  }
#pragma unroll
  for (int i = 0; i < 4; ++i)
#pragma unroll
    for (int j = 0; j < 2; ++j)
#pragma unroll
      for (int r = 0; r < 4; ++r) {
        const int row = bm + wr + i * 16 + g * 4 + r;
        const int col = bn + wc + j * 16 + ln;
        C[(size_t)row * N + col] = acc[i][j][r];
      }
}

#define TRRD(dst, base, OFFSTR) \
  asm volatile("ds_read_b64_tr_b16 %0, %1 offset:" OFFSTR : "=v"(dst) : "v"(base))

// ---- MFMA flash attention v16 (FINAL, r19/r21/r23-proven): deferred tr-unpack
// + l via ones-MFMA; K/V dbuf, single barrier; bias C-init; P ping-pong+fences.
// NOTE: s_setprio pairs are load-bearing (r22 A/B: removal broke cross-lane
// P ordering -> wrong results). Do not remove without disasm verification.
__global__ __launch_bounds__(256) void attn_mfma16(const u16* __restrict__ QKV,
                                                   const float* __restrict__ simT2,
                                                   u16* __restrict__ O) {
  __shared__ u16 Ks[2][64][36];        // [buf][kv][hd pad36]
  __shared__ u16 Vn[2][2][64][16];     // [buf][hf][kv][hd16] row-major
  __shared__ u16 Pws[4][2][16][68];    // [wave][qt][ln][kv pad68]

  const int t = threadIdx.x;
  const int lane = t & 63, w = t >> 6;
  const int g = lane >> 4, ln = lane & 15;

  // XCD-chunked remap: 1536 blocks, XCD = flat % 8.
  const int flat = blockIdx.x + 4 * (blockIdx.y + 8 * (int)blockIdx.z);
  const int work = (flat & 7) * 192 + (flat >> 3);
  const int qb = work & 3;
  const int grp = work >> 2;
  const int h = grp & 7, bt = grp >> 3;

  const size_t base = (size_t)bt * SEQ * QKVD + (size_t)h * HD;
  const u16* Qp = QKV + base;
  const u16* Kp = QKV + base + 256;
  const u16* Vp = QKV + base + 512;
  const size_t baseo = (size_t)bt * SEQ * DIM + (size_t)h * HD;
  const int wq = qb * 128 + w * 32;    // wave's first q row

  bf16x8 qf[2];   // Q pre-scaled by 1/sqrt(hd)*log2(e) via Wq
#pragma unroll
  for (int qt = 0; qt < 2; ++qt)
    qf[qt] = ldfrag16(&Qp[(size_t)(wq + qt * 16 + ln) * QKVD + g * 8]);

  const short oneb = (short)0x3F80;    // bf16 1.0
  const bf16x8 onesf = {oneb, oneb, oneb, oneb, oneb, oneb, oneb, oneb};

  const f32x4 zf = {0.f, 0.f, 0.f, 0.f};
  f32x4 o[2][2], o_l[2];
#pragma unroll
  for (int qt = 0; qt < 2; ++qt) { o[qt][0] = zf; o[qt][1] = zf; o_l[qt] = zf; }

  const float4* bq[2];
#pragma unroll
  for (int qt = 0; qt < 2; ++qt)
    bq[qt] = (const float4*)simT2 + ((size_t)g * 512 + (wq + qt * 16 + ln));

  const int sr = t >> 2, sc8 = (t & 3) * 8;
  uint4 kreg = *reinterpret_cast<const uint4*>(&Kp[(size_t)sr * QKVD + sc8]);
  uint4 vreg = *reinterpret_cast<const uint4*>(&Vp[(size_t)sr * QKVD + sc8]);

  const unsigned trbase0 = (unsigned)(unsigned long long)(&Vn[0][0][0][0])
                         + (unsigned)(g * 256 + ln * 8);

  for (int it = 0; it < 8; ++it) {
    const int buf = it & 1;
    {   // stage into buf: K as 2x b64; V one b128 (row-major)
      union { uint4 u4; uint2 u2[2]; } kv;
      kv.u4 = kreg;
      *reinterpret_cast<uint2*>(&Ks[buf][sr][sc8])     = kv.u2[0];
      *reinterpret_cast<uint2*>(&Ks[buf][sr][sc8 + 4]) = kv.u2[1];
      *reinterpret_cast<uint4*>(&Vn[buf][sc8 >> 4][sr][sc8 & 15]) = vreg;
    }
    if (it < 7) {   // prefetch next K/V tile
      const size_t off = (size_t)(it + 1) * 64 * QKVD + (size_t)sr * QKVD + sc8;
      kreg = *reinterpret_cast<const uint4*>(&Kp[off]);
      vreg = *reinterpret_cast<const uint4*>(&Vp[off]);
    }
    __syncthreads();

    // bias loads (L2 latency hides under kf reads + QK)
    float4 bc[2][4];
#pragma unroll
    for (int qt = 0; qt < 2; ++qt)
#pragma unroll
      for (int kt = 0; kt < 4; ++kt)
        bc[qt][kt] = bq[qt][kt * 2048];

    bf16x8 kf[4];
#pragma unroll
    for (int kt = 0; kt < 4; ++kt) kf[kt] = ldfrag8(&Ks[buf][kt * 16 + ln][g * 8]);

    // ISSUE tr-reads now; drain + unpack deferred until just before PV.
    u32x2 r00a, r00b, r01a, r01b, r10a, r10b, r11a, r11b;
    {
      const unsigned trb = trbase0 + (unsigned)(buf * 4096);
      TRRD(r00a, trb, "0");     TRRD(r00b, trb, "128");    // hf0 ks0
      TRRD(r01a, trb, "1024");  TRRD(r01b, trb, "1152");   // hf0 ks1
      TRRD(r10a, trb, "2048");  TRRD(r10b, trb, "2176");   // hf1 ks0
      TRRD(r11a, trb, "3072");  TRRD(r11b, trb, "3200");   // hf1 ks1
    }

    // ---- qt0: QK + exp + P-write ----
    {
      f32x4 s[4];
#pragma unroll
      for (int kt = 0; kt < 4; ++kt) {
        const float4 b4 = bc[0][kt];
        f32x4 ci = {b4.x, b4.y, b4.z, b4.w};
        s[kt] = ci;
      }
      __builtin_amdgcn_s_setprio(1);
#pragma unroll
      for (int kt = 0; kt < 4; ++kt)
        s[kt] = __builtin_amdgcn_mfma_f32_16x16x32_bf16(kf[kt], qf[0], s[kt], 0, 0, 0);
      __builtin_amdgcn_s_setprio(0);
#pragma unroll
      for (int kt = 0; kt < 4; ++kt) {
        uint2 pw;
        pw.x = cvtpk_bf16(fexp2(s[kt][0]), fexp2(s[kt][1]));
        pw.y = cvtpk_bf16(fexp2(s[kt][2]), fexp2(s[kt][3]));
        *reinterpret_cast<uint2*>(&Pws[w][0][ln][kt * 16 + g * 4]) = pw;
      }
      __builtin_amdgcn_sched_barrier(0);   // pin cross-lane P0 write order
    }

    // ---- qt1: QK + pfr0 + exp + P-write ----
    bf16x8 pfr0[2];
    {
      f32x4 s[4];
#pragma unroll
      for (int kt = 0; kt < 4; ++kt) {
        const float4 b4 = bc[1][kt];
        f32x4 ci = {b4.x, b4.y, b4.z, b4.w};
        s[kt] = ci;
      }
      __builtin_amdgcn_s_setprio(1);
#pragma unroll
      for (int kt = 0; kt < 4; ++kt)
        s[kt] = __builtin_amdgcn_mfma_f32_16x16x32_bf16(kf[kt], qf[1], s[kt], 0, 0, 0);
      __builtin_amdgcn_s_setprio(0);
#pragma unroll
      for (int ks = 0; ks < 2; ++ks)
        pfr0[ks] = ldfrag8(&Pws[w][0][ln][ks * 32 + g * 8]);
#pragma unroll
      for (int kt = 0; kt < 4; ++kt) {
        uint2 pw;
        pw.x = cvtpk_bf16(fexp2(s[kt][0]), fexp2(s[kt][1]));
        pw.y = cvtpk_bf16(fexp2(s[kt][2]), fexp2(s[kt][3]));
        *reinterpret_cast<uint2*>(&Pws[w][1][ln][kt * 16 + g * 4]) = pw;
      }
      __builtin_amdgcn_sched_barrier(0);   // pin cross-lane P1 write order
    }

    // ---- drain all DS (tr-reads long since landed; pfr0 just issued) ----
    asm volatile("s_waitcnt lgkmcnt(0)" ::: "memory");
    __builtin_amdgcn_sched_barrier(0);
    bf16x8 vf[2][2];
    {
      union { u32x2 p[2]; bf16x8 v; } u;
      u.p[0] = r00a; u.p[1] = r00b; vf[0][0] = u.v;
      u.p[0] = r01a; u.p[1] = r01b; vf[0][1] = u.v;
      u.p[0] = r10a; u.p[1] = r10b; vf[1][0] = u.v;
      u.p[0] = r11a; u.p[1] = r11b; vf[1][1] = u.v;
    }

    // ---- PV qt0 (+ l via ones-MFMA) ----
    __builtin_amdgcn_s_setprio(1);
#pragma unroll
    for (int ks = 0; ks < 2; ++ks) {
#pragma unroll
      for (int hf = 0; hf < 2; ++hf)
        o[0][hf] = __builtin_amdgcn_mfma_f32_16x16x32_bf16(pfr0[ks], vf[hf][ks], o[0][hf], 0, 0, 0);
      o_l[0] = __builtin_amdgcn_mfma_f32_16x16x32_bf16(pfr0[ks], onesf, o_l[0], 0, 0, 0);
    }
    __builtin_amdgcn_s_setprio(0);

    // ---- PV qt1 ----
    {
      bf16x8 pfr1[2];
#pragma unroll
      for (int ks = 0; ks < 2; ++ks)
        pfr1[ks] = ldfrag8(&Pws[w][1][ln][ks * 32 + g * 8]);
      __builtin_amdgcn_s_setprio(1);
#pragma unroll
      for (int ks = 0; ks < 2; ++ks) {
#pragma unroll
        for (int hf = 0; hf < 2; ++hf)
          o[1][hf] = __builtin_amdgcn_mfma_f32_16x16x32_bf16(pfr1[ks], vf[hf][ks], o[1][hf], 0, 0, 0);
        o_l[1] = __builtin_amdgcn_mfma_f32_16x16x32_bf16(pfr1[ks], onesf, o_l[1], 0, 0, 0);
      }
      __builtin_amdgcn_s_setprio(0);
    }
#pragma unroll
    for (int qt = 0; qt < 2; ++qt) bq[qt] += 16 * 512;
  }

  // epilogue: l lives in-lane (o_l[qt][r] matches o[qt][hf][r]'s q-row)
#pragma unroll
  for (int qt = 0; qt < 2; ++qt)
#pragma unroll
    for (int r = 0; r < 4; ++r) {
      const float il = 1.0f / o_l[qt][r];
      const int qrow = wq + qt * 16 + g * 4 + r;
      O[baseo + (size_t)qrow * DIM + ln]      = f2b(o[qt][0][r] * il);
      O[baseo + (size_t)qrow * DIM + 16 + ln] = f2b(o[qt][1][r] * il);
    }
}

extern "C" void kernel_launch(void* const* d_in, const int* in_sizes, int n_in,
                              void* d_out, int out_size, void* d_ws, size_t ws_size,
                              hipStream_t stream) {
  const float* x   = (const float*)d_in[0];
  const float* sim = (const float*)d_in[1];
  const float* Wq  = (const float*)d_in[2];
  const float* Wk  = (const float*)d_in[3];
  const float* Wv  = (const float*)d_in[4];
  const float* Wo  = (const float*)d_in[5];
  float* out = (float*)d_out;

  const int M = BTT * SEQ;               // 24576
  const size_t sz = (size_t)M * DIM;     // 6291456
  const int WN = DIM * DIM;              // 65536
  const float SCALE2 = 0.17677669529663687f * 1.4426950408889634f;

  u16* QKVw  = (u16*)d_ws;               // [M][768] bf16
  u16* Aw    = QKVw + (size_t)M * QKVD;  // [M][256] bf16 attention output
  u16* Wqkvb = Aw + sz;                  // [768][256] bf16 (n,k): Q|K|V
  u16* Wob   = Wqkvb + (size_t)3 * WN;   // [256][256] bf16 (n,k)
  float* simT2 = (float*)(Wob + WN);     // 1 MB packed bias (log2e-scaled)

  prep_kernel<<<dim3(4, 4, 5), 256, 0, stream>>>(Wq, Wk, Wv, Wo, sim, Wqkvb, simT2, SCALE2);

  // fused cvt + QKV projection: BN=64 -> grid 192x12 = 2304 blocks (9/CU, no tail)
  gemm_qkv64n<<<dim3(M / 128, QKVD / 64), 256, 0, stream>>>(x, Wqkvb, QKVw, M, QKVD, DIM);

  attn_mfma16<<<dim3(4, NH, BTT), 256, 0, stream>>>(QKVw, simT2, Aw);

  // O projection: BN=64, BK=64 (split k-half buffers), grid 192x4 = 768 blocks
  gemm_o64<<<dim3(M / 128, DIM / 64), 256, 0, stream>>>(Aw, Wob, out, M, DIM, DIM);
}

// Round 25
// 75.759 us; speedup vs baseline: 1.0506x; 1.0506x over previous
//
#include <hip/hip_runtime.h>
#include <hip/hip_bf16.h>

#define BTT 48      // B*T
#define SEQ 512     // spatial tokens
#define DIM 256     // model dim
#define NH  8       // heads
#define HD  32      // head dim
#define QKVD 768    // fused QKV row stride

typedef unsigned short u16;
typedef __attribute__((ext_vector_type(8))) short bf16x8;
typedef __attribute__((ext_vector_type(4))) float f32x4;
typedef __attribute__((ext_vector_type(2))) unsigned int u32x2;

__device__ __forceinline__ float fexp2(float x) {
#if __has_builtin(__builtin_amdgcn_exp2f)
  return __builtin_amdgcn_exp2f(x);
#else
  float r; asm("v_exp_f32 %0, %1" : "=v"(r) : "v"(x)); return r;
#endif
}
__device__ __forceinline__ unsigned cvtpk_bf16(float lo, float hi) {
  unsigned r;
  asm("v_cvt_pk_bf16_f32 %0, %1, %2" : "=v"(r) : "v"(lo), "v"(hi));
  return r;
}

__device__ __forceinline__ u16 f2b(float f) {
  __hip_bfloat16 h = __float2bfloat16(f);
  union { __hip_bfloat16 h; u16 u; } c; c.h = h; return c.u;
}
__device__ __forceinline__ bf16x8 ldfrag8(const u16* p) {   // LDS, 8B-aligned
  union { uint2 u[2]; bf16x8 v; } f;
  f.u[0] = *reinterpret_cast<const uint2*>(p);
  f.u[1] = *reinterpret_cast<const uint2*>(p + 4);
  return f.v;
}
__device__ __forceinline__ bf16x8 ldfrag16(const u16* p) {  // 16B-aligned
  union { uint4 u; bf16x8 v; } f;
  f.u = *reinterpret_cast<const uint4*>(p);
  return f.v;
}

// ---- merged prep: z<4 = weight cvt+transpose+scale; z==4 = sim pack ----
__global__ __launch_bounds__(256) void prep_kernel(const float* __restrict__ W0,
                                                   const float* __restrict__ W1,
                                                   const float* __restrict__ W2,
                                                   const float* __restrict__ W3,
                                                   const float* __restrict__ sim,
                                                   u16* __restrict__ dst,
                                                   float* __restrict__ simT2,
                                                   float sc0) {
  __shared__ float Ls[64][65];
  const int z = blockIdx.z;
  const int t = threadIdx.x;
  if (z == 4) {   // sim[q][k] fp32 -> simT2[k>>2][q][k&3], scaled by log2(e)
    const float LOG2E = 1.4426950408889634f;
    const int b = blockIdx.x * 4 + blockIdx.y;     // 0..15
#pragma unroll
    for (int i = 0; i < 16; ++i) {
      int gid = b * 4096 + i * 256 + t;            // 0..65535
      int q = gid & 511, k4 = gid >> 9;
      float4 v = *reinterpret_cast<const float4*>(&sim[(size_t)q * 512 + k4 * 4]);
      v.x *= LOG2E; v.y *= LOG2E; v.z *= LOG2E; v.w *= LOG2E;
      *reinterpret_cast<float4*>(&simT2[((size_t)k4 * 512 + q) * 4]) = v;
    }
    return;
  }
  const float* W = (z == 0) ? W0 : (z == 1) ? W1 : (z == 2) ? W2 : W3;
  u16* Bt = dst + (size_t)z * DIM * DIM;
  const float sc = (z == 0) ? sc0 : 1.0f;
  const int kt = blockIdx.x * 64, nt = blockIdx.y * 64;
#pragma unroll
  for (int it = 0; it < 4; ++it) {
    int r = (t >> 4) + it * 16;
    int c = (t & 15) * 4;
    float4 v = *reinterpret_cast<const float4*>(&W[(size_t)(kt + r) * 256 + nt + c]);
    Ls[r][c] = v.x; Ls[r][c + 1] = v.y; Ls[r][c + 2] = v.z; Ls[r][c + 3] = v.w;
  }
  __syncthreads();
  const int n = t >> 2, kc = (t & 3) * 16;
  union { uint4 u[2]; u16 s[16]; } ob;
#pragma unroll
  for (int j = 0; j < 16; ++j) ob.s[j] = f2b(Ls[kc + j][n] * sc);
  u16* dp = Bt + (size_t)(nt + n) * 256 + kt + kc;
  *reinterpret_cast<uint4*>(dp)     = ob.u[0];
  *reinterpret_cast<uint4*>(dp + 8) = ob.u[1];
}

// ---- MFMA GEMM (QKV): BK=32, BN=128, fp32-A fused cvt, XCD-chunked swizzle ----
__global__ __launch_bounds__(256) void gemm_qkv(const float* __restrict__ A,
                                                const u16* __restrict__ Bt,
                                                u16* __restrict__ C,
                                                int M, int N, int K) {
  __shared__ u16 As[128][36];
  __shared__ u16 Bs[128][36];
  const int t = threadIdx.x, lane = t & 63, w = t >> 6;
  const int g = lane >> 4, ln = lane & 15;

  const int gx = gridDim.x, gy = gridDim.y;
  const int flat = blockIdx.x + gx * blockIdx.y;
  const int chunk = (gx * gy) >> 3;
  const int work = (flat & 7) * chunk + (flat >> 3);
  const int bm = (work / gy) * 128, bn = (work % gy) * 128;

  const int wr = (w & 1) * 64, wc = (w >> 1) * 64;
  const f32x4 zf = {0.f, 0.f, 0.f, 0.f};
  f32x4 acc[4][4];
#pragma unroll
  for (int i = 0; i < 4; ++i)
#pragma unroll
    for (int j = 0; j < 4; ++j) acc[i][j] = zf;

  const int r0 = t >> 2, c8 = (t & 3) * 8;
  uint4 bpre[2];
  float4 apf0[2], apf1[2];
#pragma unroll
  for (int p = 0; p < 2; ++p) {
    const size_t arow = (size_t)(bm + r0 + p * 64) * K + c8;
    apf0[p] = *reinterpret_cast<const float4*>(A + arow);
    apf1[p] = *reinterpret_cast<const float4*>(A + arow + 4);
    bpre[p] = *reinterpret_cast<const uint4*>(&Bt[(size_t)(bn + r0 + p * 64) * K + c8]);
  }

  for (int k0 = 0; k0 < K; k0 += 32) {
#pragma unroll
    for (int p = 0; p < 2; ++p) {
      const int r = r0 + p * 64;
      uint2 a0, a1;
      a0.x = cvtpk_bf16(apf0[p].x, apf0[p].y);
      a0.y = cvtpk_bf16(apf0[p].z, apf0[p].w);
      a1.x = cvtpk_bf16(apf1[p].x, apf1[p].y);
      a1.y = cvtpk_bf16(apf1[p].z, apf1[p].w);
      union { uint4 u4; uint2 u2[2]; } bv; bv.u4 = bpre[p];
      *reinterpret_cast<uint2*>(&As[r][c8])     = a0;
      *reinterpret_cast<uint2*>(&As[r][c8 + 4]) = a1;
      *reinterpret_cast<uint2*>(&Bs[r][c8])     = bv.u2[0];
      *reinterpret_cast<uint2*>(&Bs[r][c8 + 4]) = bv.u2[1];
    }
    if (k0 + 32 < K) {
#pragma unroll
      for (int p = 0; p < 2; ++p) {
        const size_t arow = (size_t)(bm + r0 + p * 64) * K + k0 + 32 + c8;
        apf0[p] = *reinterpret_cast<const float4*>(A + arow);
        apf1[p] = *reinterpret_cast<const float4*>(A + arow + 4);
        bpre[p] = *reinterpret_cast<const uint4*>(&Bt[(size_t)(bn + r0 + p * 64) * K + k0 + 32 + c8]);
      }
    }
    __syncthreads();
    bf16x8 af[4], bfr[4];
#pragma unroll
    for (int i = 0; i < 4; ++i) af[i]  = ldfrag8(&As[wr + i * 16 + ln][g * 8]);
#pragma unroll
    for (int j = 0; j < 4; ++j) bfr[j] = ldfrag8(&Bs[wc + j * 16 + ln][g * 8]);
#pragma unroll
    for (int i = 0; i < 4; ++i)
#pragma unroll
      for (int j = 0; j < 4; ++j)
        acc[i][j] = __builtin_amdgcn_mfma_f32_16x16x32_bf16(af[i], bfr[j], acc[i][j], 0, 0, 0);
    __syncthreads();
  }
#pragma unroll
  for (int i = 0; i < 4; ++i)
#pragma unroll
    for (int j = 0; j < 4; ++j)
#pragma unroll
      for (int r = 0; r < 4; ++r) {
        const int row = bm + wr + i * 16 + g * 4 + r;
        const int col = bn + wc + j * 16 + ln;
        C[(size_t)row * N + col] = f2b(acc[i][j][r]);
      }
}

// ---- O-projection GEMM: bf16 A, BN=64, BK=64 via split k-half buffers ----
__global__ __launch_bounds__(256) void gemm_o64(const u16* __restrict__ A,
                                                const u16* __restrict__ Bt,
                                                float* __restrict__ C,
                                                int M, int N, int K) {
  __shared__ u16 As[2][128][36];   // [k-half][m][k32 pad36]
  __shared__ u16 Bs[2][64][36];    // [k-half][n][k32 pad36]
  const int t = threadIdx.x, lane = t & 63, w = t >> 6;
  const int g = lane >> 4, ln = lane & 15;

  const int gx = gridDim.x, gy = gridDim.y;
  const int flat = blockIdx.x + gx * blockIdx.y;
  const int chunk = (gx * gy) >> 3;
  const int work = (flat & 7) * chunk + (flat >> 3);
  const int bm = (work / gy) * 128, bn = (work % gy) * 64;

  const int wr = (w & 1) * 64, wc = (w >> 1) * 32;
  const f32x4 zf = {0.f, 0.f, 0.f, 0.f};
  f32x4 acc[4][2];
#pragma unroll
  for (int i = 0; i < 4; ++i) { acc[i][0] = zf; acc[i][1] = zf; }

  const int ra = t >> 2, ca = t & 3;
  const int ch = ca >> 1, co = (ca & 1) * 16;
  uint4 apre[2][2], bpre[2];
#pragma unroll
  for (int p = 0; p < 2; ++p) {
    const size_t arow = (size_t)(bm + ra + p * 64) * K + ca * 16;
    apre[p][0] = *reinterpret_cast<const uint4*>(A + arow);
    apre[p][1] = *reinterpret_cast<const uint4*>(A + arow + 8);
  }
  {
    const size_t brow = (size_t)(bn + ra) * K + ca * 16;
    bpre[0] = *reinterpret_cast<const uint4*>(Bt + brow);
    bpre[1] = *reinterpret_cast<const uint4*>(Bt + brow + 8);
  }

  for (int k0 = 0; k0 < K; k0 += 64) {
#pragma unroll
    for (int p = 0; p < 2; ++p) {
      u16* dst = &As[ch][ra + p * 64][co];
      union { uint4 u4; uint2 u2[2]; } v0, v1;
      v0.u4 = apre[p][0]; v1.u4 = apre[p][1];
      *reinterpret_cast<uint2*>(dst)      = v0.u2[0];
      *reinterpret_cast<uint2*>(dst + 4)  = v0.u2[1];
      *reinterpret_cast<uint2*>(dst + 8)  = v1.u2[0];
      *reinterpret_cast<uint2*>(dst + 12) = v1.u2[1];
    }
    {
      u16* dst = &Bs[ch][ra][co];
      union { uint4 u4; uint2 u2[2]; } v0, v1;
      v0.u4 = bpre[0]; v1.u4 = bpre[1];
      *reinterpret_cast<uint2*>(dst)      = v0.u2[0];
      *reinterpret_cast<uint2*>(dst + 4)  = v0.u2[1];
      *reinterpret_cast<uint2*>(dst + 8)  = v1.u2[0];
      *reinterpret_cast<uint2*>(dst + 12) = v1.u2[1];
    }
    if (k0 + 64 < K) {
#pragma unroll
      for (int p = 0; p < 2; ++p) {
        const size_t arow = (size_t)(bm + ra + p * 64) * K + k0 + 64 + ca * 16;
        apre[p][0] = *reinterpret_cast<const uint4*>(A + arow);
        apre[p][1] = *reinterpret_cast<const uint4*>(A + arow + 8);
      }
      const size_t brow = (size_t)(bn + ra) * K + k0 + 64 + ca * 16;
      bpre[0] = *reinterpret_cast<const uint4*>(Bt + brow);
      bpre[1] = *reinterpret_cast<const uint4*>(Bt + brow + 8);
    }
    __syncthreads();
#pragma unroll
    for (int kk = 0; kk < 2; ++kk) {
      bf16x8 af[4], bfr[2];
#pragma unroll
      for (int i = 0; i < 4; ++i) af[i]  = ldfrag8(&As[kk][wr + i * 16 + ln][g * 8]);
#pragma unroll
      for (int j = 0; j < 2; ++j) bfr[j] = ldfrag8(&Bs[kk][wc + j * 16 + ln][g * 8]);
#pragma unroll
      for (int i = 0; i < 4; ++i)
#pragma unroll
        for (int j = 0; j < 2; ++j)
          acc[i][j] = __builtin_amdgcn_mfma_f32_16x16x32_bf16(af[i], bfr[j], acc[i][j], 0, 0, 0);
    }
    __syncthreads();
  }
#pragma unroll
  for (int i = 0; i < 4; ++i)
#pragma unroll
    for (int j = 0; j < 2; ++j)
#pragma unroll
      for (int r = 0; r < 4; ++r) {
        const int row = bm + wr + i * 16 + g * 4 + r;
        const int col = bn + wc + j * 16 + ln;
        C[(size_t)row * N + col] = acc[i][j][r];
      }
}

#define TRRD(dst, base, OFFSTR) \
  asm volatile("ds_read_b64_tr_b16 %0, %1 offset:" OFFSTR : "=v"(dst) : "v"(base))

// ---- MFMA flash attention v16 (FINAL, r19/r21/r23-proven): deferred tr-unpack
// + l via ones-MFMA; K/V dbuf, single barrier; bias C-init; P ping-pong+fences.
// NOTE: s_setprio pairs are load-bearing (r22 A/B: removal broke cross-lane
// P ordering -> wrong results). Do not remove without disasm verification.
__global__ __launch_bounds__(256) void attn_mfma16(const u16* __restrict__ QKV,
                                                   const float* __restrict__ simT2,
                                                   u16* __restrict__ O) {
  __shared__ u16 Ks[2][64][36];        // [buf][kv][hd pad36]
  __shared__ u16 Vn[2][2][64][16];     // [buf][hf][kv][hd16] row-major
  __shared__ u16 Pws[4][2][16][68];    // [wave][qt][ln][kv pad68]

  const int t = threadIdx.x;
  const int lane = t & 63, w = t >> 6;
  const int g = lane >> 4, ln = lane & 15;

  // XCD-chunked remap: 1536 blocks, XCD = flat % 8.
  const int flat = blockIdx.x + 4 * (blockIdx.y + 8 * (int)blockIdx.z);
  const int work = (flat & 7) * 192 + (flat >> 3);
  const int qb = work & 3;
  const int grp = work >> 2;
  const int h = grp & 7, bt = grp >> 3;

  const size_t base = (size_t)bt * SEQ * QKVD + (size_t)h * HD;
  const u16* Qp = QKV + base;
  const u16* Kp = QKV + base + 256;
  const u16* Vp = QKV + base + 512;
  const size_t baseo = (size_t)bt * SEQ * DIM + (size_t)h * HD;
  const int wq = qb * 128 + w * 32;    // wave's first q row

  bf16x8 qf[2];   // Q pre-scaled by 1/sqrt(hd)*log2(e) via Wq
#pragma unroll
  for (int qt = 0; qt < 2; ++qt)
    qf[qt] = ldfrag16(&Qp[(size_t)(wq + qt * 16 + ln) * QKVD + g * 8]);

  const short oneb = (short)0x3F80;    // bf16 1.0
  const bf16x8 onesf = {oneb, oneb, oneb, oneb, oneb, oneb, oneb, oneb};

  const f32x4 zf = {0.f, 0.f, 0.f, 0.f};
  f32x4 o[2][2], o_l[2];
#pragma unroll
  for (int qt = 0; qt < 2; ++qt) { o[qt][0] = zf; o[qt][1] = zf; o_l[qt] = zf; }

  const float4* bq[2];
#pragma unroll
  for (int qt = 0; qt < 2; ++qt)
    bq[qt] = (const float4*)simT2 + ((size_t)g * 512 + (wq + qt * 16 + ln));

  const int sr = t >> 2, sc8 = (t & 3) * 8;
  uint4 kreg = *reinterpret_cast<const uint4*>(&Kp[(size_t)sr * QKVD + sc8]);
  uint4 vreg = *reinterpret_cast<const uint4*>(&Vp[(size_t)sr * QKVD + sc8]);

  const unsigned trbase0 = (unsigned)(unsigned long long)(&Vn[0][0][0][0])
                         + (unsigned)(g * 256 + ln * 8);

  for (int it = 0; it < 8; ++it) {
    const int buf = it & 1;
    {   // stage into buf: K as 2x b64; V one b128 (row-major)
      union { uint4 u4; uint2 u2[2]; } kv;
      kv.u4 = kreg;
      *reinterpret_cast<uint2*>(&Ks[buf][sr][sc8])     = kv.u2[0];
      *reinterpret_cast<uint2*>(&Ks[buf][sr][sc8 + 4]) = kv.u2[1];
      *reinterpret_cast<uint4*>(&Vn[buf][sc8 >> 4][sr][sc8 & 15]) = vreg;
    }
    if (it < 7) {   // prefetch next K/V tile
      const size_t off = (size_t)(it + 1) * 64 * QKVD + (size_t)sr * QKVD + sc8;
      kreg = *reinterpret_cast<const uint4*>(&Kp[off]);
      vreg = *reinterpret_cast<const uint4*>(&Vp[off]);
    }
    __syncthreads();

    // bias loads (L2 latency hides under kf reads + QK)
    float4 bc[2][4];
#pragma unroll
    for (int qt = 0; qt < 2; ++qt)
#pragma unroll
      for (int kt = 0; kt < 4; ++kt)
        bc[qt][kt] = bq[qt][kt * 2048];

    bf16x8 kf[4];
#pragma unroll
    for (int kt = 0; kt < 4; ++kt) kf[kt] = ldfrag8(&Ks[buf][kt * 16 + ln][g * 8]);

    // ISSUE tr-reads now; drain + unpack deferred until just before PV.
    u32x2 r00a, r00b, r01a, r01b, r10a, r10b, r11a, r11b;
    {
      const unsigned trb = trbase0 + (unsigned)(buf * 4096);
      TRRD(r00a, trb, "0");     TRRD(r00b, trb, "128");    // hf0 ks0
      TRRD(r01a, trb, "1024");  TRRD(r01b, trb, "1152");   // hf0 ks1
      TRRD(r10a, trb, "2048");  TRRD(r10b, trb, "2176");   // hf1 ks0
      TRRD(r11a, trb, "3072");  TRRD(r11b, trb, "3200");   // hf1 ks1
    }

    // ---- qt0: QK + exp + P-write ----
    {
      f32x4 s[4];
#pragma unroll
      for (int kt = 0; kt < 4; ++kt) {
        const float4 b4 = bc[0][kt];
        f32x4 ci = {b4.x, b4.y, b4.z, b4.w};
        s[kt] = ci;
      }
      __builtin_amdgcn_s_setprio(1);
#pragma unroll
      for (int kt = 0; kt < 4; ++kt)
        s[kt] = __builtin_amdgcn_mfma_f32_16x16x32_bf16(kf[kt], qf[0], s[kt], 0, 0, 0);
      __builtin_amdgcn_s_setprio(0);
#pragma unroll
      for (int kt = 0; kt < 4; ++kt) {
        uint2 pw;
        pw.x = cvtpk_bf16(fexp2(s[kt][0]), fexp2(s[kt][1]));
        pw.y = cvtpk_bf16(fexp2(s[kt][2]), fexp2(s[kt][3]));
        *reinterpret_cast<uint2*>(&Pws[w][0][ln][kt * 16 + g * 4]) = pw;
      }
      __builtin_amdgcn_sched_barrier(0);   // pin cross-lane P0 write order
    }

    // ---- qt1: QK + pfr0 + exp + P-write ----
    bf16x8 pfr0[2];
    {
      f32x4 s[4];
#pragma unroll
      for (int kt = 0; kt < 4; ++kt) {
        const float4 b4 = bc[1][kt];
        f32x4 ci = {b4.x, b4.y, b4.z, b4.w};
        s[kt] = ci;
      }
      __builtin_amdgcn_s_setprio(1);
#pragma unroll
      for (int kt = 0; kt < 4; ++kt)
        s[kt] = __builtin_amdgcn_mfma_f32_16x16x32_bf16(kf[kt], qf[1], s[kt], 0, 0, 0);
      __builtin_amdgcn_s_setprio(0);
#pragma unroll
      for (int ks = 0; ks < 2; ++ks)
        pfr0[ks] = ldfrag8(&Pws[w][0][ln][ks * 32 + g * 8]);
#pragma unroll
      for (int kt = 0; kt < 4; ++kt) {
        uint2 pw;
        pw.x = cvtpk_bf16(fexp2(s[kt][0]), fexp2(s[kt][1]));
        pw.y = cvtpk_bf16(fexp2(s[kt][2]), fexp2(s[kt][3]));
        *reinterpret_cast<uint2*>(&Pws[w][1][ln][kt * 16 + g * 4]) = pw;
      }
      __builtin_amdgcn_sched_barrier(0);   // pin cross-lane P1 write order
    }

    // ---- drain all DS (tr-reads long since landed; pfr0 just issued) ----
    asm volatile("s_waitcnt lgkmcnt(0)" ::: "memory");
    __builtin_amdgcn_sched_barrier(0);
    bf16x8 vf[2][2];
    {
      union { u32x2 p[2]; bf16x8 v; } u;
      u.p[0] = r00a; u.p[1] = r00b; vf[0][0] = u.v;
      u.p[0] = r01a; u.p[1] = r01b; vf[0][1] = u.v;
      u.p[0] = r10a; u.p[1] = r10b; vf[1][0] = u.v;
      u.p[0] = r11a; u.p[1] = r11b; vf[1][1] = u.v;
    }

    // ---- PV qt0 (+ l via ones-MFMA) ----
    __builtin_amdgcn_s_setprio(1);
#pragma unroll
    for (int ks = 0; ks < 2; ++ks) {
#pragma unroll
      for (int hf = 0; hf < 2; ++hf)
        o[0][hf] = __builtin_amdgcn_mfma_f32_16x16x32_bf16(pfr0[ks], vf[hf][ks], o[0][hf], 0, 0, 0);
      o_l[0] = __builtin_amdgcn_mfma_f32_16x16x32_bf16(pfr0[ks], onesf, o_l[0], 0, 0, 0);
    }
    __builtin_amdgcn_s_setprio(0);

    // ---- PV qt1 ----
    {
      bf16x8 pfr1[2];
#pragma unroll
      for (int ks = 0; ks < 2; ++ks)
        pfr1[ks] = ldfrag8(&Pws[w][1][ln][ks * 32 + g * 8]);
      __builtin_amdgcn_s_setprio(1);
#pragma unroll
      for (int ks = 0; ks < 2; ++ks) {
#pragma unroll
        for (int hf = 0; hf < 2; ++hf)
          o[1][hf] = __builtin_amdgcn_mfma_f32_16x16x32_bf16(pfr1[ks], vf[hf][ks], o[1][hf], 0, 0, 0);
        o_l[1] = __builtin_amdgcn_mfma_f32_16x16x32_bf16(pfr1[ks], onesf, o_l[1], 0, 0, 0);
      }
      __builtin_amdgcn_s_setprio(0);
    }
#pragma unroll
    for (int qt = 0; qt < 2; ++qt) bq[qt] += 16 * 512;
  }

  // epilogue: l lives in-lane (o_l[qt][r] matches o[qt][hf][r]'s q-row)
#pragma unroll
  for (int qt = 0; qt < 2; ++qt)
#pragma unroll
    for (int r = 0; r < 4; ++r) {
      const float il = 1.0f / o_l[qt][r];
      const int qrow = wq + qt * 16 + g * 4 + r;
      O[baseo + (size_t)qrow * DIM + ln]      = f2b(o[qt][0][r] * il);
      O[baseo + (size_t)qrow * DIM + 16 + ln] = f2b(o[qt][1][r] * il);
    }
}

extern "C" void kernel_launch(void* const* d_in, const int* in_sizes, int n_in,
                              void* d_out, int out_size, void* d_ws, size_t ws_size,
                              hipStream_t stream) {
  const float* x   = (const float*)d_in[0];
  const float* sim = (const float*)d_in[1];
  const float* Wq  = (const float*)d_in[2];
  const float* Wk  = (const float*)d_in[3];
  const float* Wv  = (const float*)d_in[4];
  const float* Wo  = (const float*)d_in[5];
  float* out = (float*)d_out;

  const int M = BTT * SEQ;               // 24576
  const size_t sz = (size_t)M * DIM;     // 6291456
  const int WN = DIM * DIM;              // 65536
  const float SCALE2 = 0.17677669529663687f * 1.4426950408889634f;

  u16* QKVw  = (u16*)d_ws;               // [M][768] bf16
  u16* Aw    = QKVw + (size_t)M * QKVD;  // [M][256] bf16 attention output
  u16* Wqkvb = Aw + sz;                  // [768][256] bf16 (n,k): Q|K|V
  u16* Wob   = Wqkvb + (size_t)3 * WN;   // [256][256] bf16 (n,k)
  float* simT2 = (float*)(Wob + WN);     // 1 MB packed bias (log2e-scaled)

  prep_kernel<<<dim3(4, 4, 5), 256, 0, stream>>>(Wq, Wk, Wv, Wo, sim, Wqkvb, simT2, SCALE2);

  // fused cvt + QKV projection: fp32 [M,256] x bf16 [256,768] -> bf16 [M,768]
  gemm_qkv<<<dim3(M / 128, QKVD / 128), 256, 0, stream>>>(x, Wqkvb, QKVw, M, QKVD, DIM);

  attn_mfma16<<<dim3(4, NH, BTT), 256, 0, stream>>>(QKVw, simT2, Aw);

  // O projection: BN=64, BK=64 (split k-half buffers), grid 192x4 = 768 blocks
  gemm_o64<<<dim3(M / 128, DIM / 64), 256, 0, stream>>>(Aw, Wob, out, M, DIM, DIM);
}